// Round 5
// baseline (2637.177 us; speedup 1.0000x reference)
//
#include <hip/hip_runtime.h>
#include <cstdint>
#include <cstddef>

#define XDIM 128
#define HDIM 1024
#define ORS 8192   /* out/input row stride = T*XD */
#define NPH 129

typedef __attribute__((ext_vector_type(8))) short short8;
typedef __attribute__((ext_vector_type(4))) float f32x4;

static const size_t GSTRIDE = (size_t)36 * 64 * 64 * 8;  // shorts per gate group
static const size_t EPACK   = 4 * GSTRIDE;               // shorts per enc/dec pack

struct Phase {
  float spA, spB, nsA, nsB, qsA, qsB, q2sA, q2sB;
  int ebase, xe, xd, afrag;
  int hpA, hpB, nskip, qskip, q2skip;
  int anext, pnext, p2next, hout;
  int pfrag, pouti, pxout;
};
static_assert(sizeof(Phase) == 96, "phase size");

__device__ __forceinline__ unsigned short f2bf(float f) {
  union { float f; unsigned u; } c; c.f = f;
  unsigned u = c.u + (0x7fffu + ((c.u >> 16) & 1u));  // RNE; finite inputs
  return (unsigned short)(u >> 16);
}
__device__ __forceinline__ float sigm_(float x) { return 1.f / (1.f + __expf(-x)); }
__device__ __forceinline__ float tanh_(float x) { return 2.f / (1.f + __expf(-2.f * x)) - 1.f; }

__device__ __forceinline__ short8 cvt8(float4 a, float4 b) {
  short8 o;
  o[0] = (short)f2bf(a.x); o[1] = (short)f2bf(a.y); o[2] = (short)f2bf(a.z); o[3] = (short)f2bf(a.w);
  o[4] = (short)f2bf(b.x); o[5] = (short)f2bf(b.y); o[6] = (short)f2bf(b.z); o[7] = (short)f2bf(b.w);
  return o;
}

// ---- coherence-point (IF$) accesses: bypass L1+L2, NO cache maintenance ----
__device__ __forceinline__ unsigned long long ld64_sys(const unsigned short* p) {
  return __hip_atomic_load((const unsigned long long*)p, __ATOMIC_RELAXED,
                           __HIP_MEMORY_SCOPE_SYSTEM);
}
__device__ __forceinline__ unsigned ld32_sys(const unsigned* p) {
  return __hip_atomic_load(p, __ATOMIC_RELAXED, __HIP_MEMORY_SCOPE_SYSTEM);
}
__device__ __forceinline__ void st32_sys(unsigned* p, unsigned v) {
  __hip_atomic_store(p, v, __ATOMIC_RELAXED, __HIP_MEMORY_SCOPE_SYSTEM);
}
union U128 { unsigned long long u[2]; short8 v; };
__device__ __forceinline__ short8 mk8(unsigned long long a, unsigned long long b) {
  U128 u; u.u[0] = a; u.u[1] = b; return u.v;
}
// lane-pair (even/odd cols) combine -> one 4B coherent store by even lane
__device__ __forceinline__ void st_pair_bf(unsigned short* addr, int lane, unsigned short v) {
  unsigned other = (unsigned)__shfl_xor((int)(unsigned)v, 1);
  if ((lane & 1) == 0)
    st32_sys((unsigned*)addr, ((unsigned)v & 0xffffu) | (other << 16));
}

#define MFMA(a,b,c) __builtin_amdgcn_mfma_f32_16x16x32_bf16((a),(b),(c),0,0,0)

// ---------------- prep kernels ----------------
__global__ __launch_bounds__(256) void pack_gates(
    const float* __restrict__ eWih, const float* __restrict__ eWhh,
    const float* __restrict__ dWih, const float* __restrict__ dWhh,
    short* __restrict__ Bg)
{
  unsigned t = blockIdx.x * 256u + threadIdx.x;   // 2*4*36*64*64 = 1,179,648
  unsigned l  = t & 63u; t >>= 6;
  unsigned nf = t & 63u; t >>= 6;
  unsigned ks = t % 36u; t /= 36u;
  unsigned g  = t & 3u;  t >>= 2;
  if (t >= 2u) return;
  if ((g == 2u && ks >= 4u) || (g == 3u && ks < 4u)) return;
  const float* Wih = t ? dWih : eWih;
  const float* Whh = t ? dWhh : eWhh;
  int k = (int)(ks * 32u + (l >> 4) * 8u);
  int n = (int)(nf * 16u + (l & 15u));
  const float* src;
  if (g == 3u)      src = Whh + (size_t)(2048 + n) * HDIM + (k - XDIM);
  else if (g == 2u) src = Wih + (size_t)(2048 + n) * XDIM + k;
  else if (ks < 4u) src = Wih + (size_t)(g * HDIM + n) * XDIM + k;
  else              src = Whh + (size_t)(g * HDIM + n) * HDIM + (k - XDIM);
  float4 a = *(const float4*)src;
  float4 b = *(const float4*)(src + 4);
  size_t off = ((((size_t)t * 4u + g) * 36u + ks) * 64u + nf) * 64u + l;
  *(short8*)(Bg + off * 8u) = cvt8(a, b);
}

__global__ __launch_bounds__(256) void pack_lin(const float* __restrict__ linW,
                                                short* __restrict__ Bl)
{
  unsigned t = blockIdx.x * 256u + threadIdx.x;   // 32*8*64 = 16384
  unsigned l  = t & 63u; t >>= 6;
  unsigned nf = t & 7u;  t >>= 3;
  unsigned ks = t;
  if (ks >= 32u) return;
  int k = (int)(ks * 32u + (l >> 4) * 8u);
  int n = (int)(nf * 16u + (l & 15u));
  const float* src = linW + (size_t)n * HDIM + k;
  float4 a = *(const float4*)src;
  float4 b = *(const float4*)(src + 4);
  *(short8*)(Bl + (((size_t)ks * 8u + nf) * 64u + l) * 8u) = cvt8(a, b);
}

__global__ __launch_bounds__(256) void pack_bias(
    const float* __restrict__ eIh, const float* __restrict__ eHh,
    const float* __restrict__ dIh, const float* __restrict__ dHh,
    float* __restrict__ bias)  // [2][4][1024]
{
  unsigned t = blockIdx.x * 256u + threadIdx.x;
  if (t >= 8192u) return;
  unsigned n = t & 1023u, g = (t >> 10) & 3u, e = t >> 12;
  const float* bih = e ? dIh : eIh;
  const float* bhh = e ? dHh : eHh;
  float v;
  if (g == 0u)      v = bih[n] + bhh[n];
  else if (g == 1u) v = bih[HDIM + n] + bhh[HDIM + n];
  else if (g == 2u) v = bih[2 * HDIM + n];
  else              v = bhh[2 * HDIM + n];
  bias[t] = v;
}

// enc input -> frag-major bf16: Xe[i][ks4][lq4][row256][8]
__global__ __launch_bounds__(256) void pack_x(const float* __restrict__ in,
                                              unsigned short* __restrict__ Xe)
{
  unsigned t = blockIdx.x * 256u + threadIdx.x;   // 64*4*4*256 = 262,144
  unsigned row = t & 255u; t >>= 8;
  unsigned lq  = t & 3u;   t >>= 2;
  unsigned ks  = t & 3u;   t >>= 2;
  unsigned i   = t;
  if (i >= 64u) return;
  const float* src = in + (size_t)row * ORS + i * 128u + ks * 32u + lq * 8u;
  float4 a = *(const float4*)src;
  float4 b = *(const float4*)(src + 4);
  *(short8*)(Xe + ((((size_t)i * 4u + ks) * 4u + lq) * 256u + row) * 8u) = cvt8(a, b);
}

// ---------------- phase-table builder (1 thread) ----------------
__device__ __forceinline__ int mkslot(int s) { return s % 12; }

__device__ void blank_phase(Phase& ph) {
  ph.spA = ph.spB = ph.nsA = ph.nsB = ph.qsA = ph.qsB = ph.q2sA = ph.q2sB = 0.f;
  ph.ebase = 0; ph.xe = -1; ph.xd = -1; ph.afrag = -1;
  ph.hpA = ph.hpB = ph.nskip = ph.qskip = ph.q2skip = 0;
  ph.anext = ph.pnext = ph.p2next = -1; ph.hout = -1;
  ph.pfrag = -1; ph.pouti = -1; ph.pxout = -1;
}

__global__ void setup_phases(Phase* __restrict__ phs, unsigned* __restrict__ arr) {
  const int t = threadIdx.x;
  for (int k = t; k < 1024; k += 64) arr[k] = 0u;   // zero barrier slots
  if (t != 0) return;

  // numpy-legacy MT19937, RandomState(0)
  unsigned mt[624];
  mt[0] = 0u;
  for (int i = 1; i < 624; ++i)
    mt[i] = 1812433253u * (mt[i - 1] ^ (mt[i - 1] >> 30)) + (unsigned)i;
  for (int i = 0; i < 624; ++i) {
    unsigned y = (mt[i] & 0x80000000u) | (mt[(i + 1) % 624] & 0x7fffffffu);
    unsigned v = mt[(i + 397) % 624] ^ (y >> 1);
    mt[i] = (y & 1u) ? (v ^ 0x9908b0dfu) : v;
  }
  int mti = 0;
  float ew[64][2], dw[64][2];
  for (int e = 0; e < 2; ++e) {
    for (int i = 0; i < 64; ++i) {
      unsigned y = mt[mti++];
      y ^= y >> 11; y ^= (y << 7) & 0x9d2c5680u; y ^= (y << 15) & 0xefc60000u; y ^= y >> 18;
      int w1 = (int)(y & 1u);
      int w2 = 1;
      if (w1 != 0) {
        unsigned z = mt[mti++];
        z ^= z >> 11; z ^= (z << 7) & 0x9d2c5680u; z ^= (z << 15) & 0xefc60000u; z ^= z >> 18;
        w2 = (int)(z & 1u);
      }
      if (e == 0) { ew[i][0] = (float)w1; ew[i][1] = (float)w2; }
      else        { dw[i][0] = (float)w1; dw[i][1] = (float)w2; }
    }
  }

  bool anull = true;  // An consumed by next cell phase is all-zero?
  // ---- encoder phases 0..63 (global step s = i) ----
  for (int i = 0; i < 64; ++i) {
    Phase ph; blank_phase(ph);
    ph.ebase = 0; ph.xe = i;
    ph.hout = mkslot(i);
    if (i >= 1 && !anull) ph.afrag = i & 3;
    ph.hpA = mkslot(i >= 1 ? i - 1 : 0);
    ph.spA = i ? ew[i][0] : 0.f;
    if (i == 3)       { ph.hpB = mkslot(1);      ph.spB = ew[i][1]; }
    else if (i == 4)  { ph.hpB = mkslot(3);      ph.spB = ew[i][1]; }
    else if (i >= 10) { ph.hpB = mkslot(i - 10); ph.spB = ew[i][1]; }
    if (i < 63) {
      int n = i + 1;
      ph.anext = n & 3;
      if (n == 4) ph.nsA = ew[4][0] + ew[4][1];      // skip source IS h_new (h3)
      else {
        ph.nsA = ew[n][0];
        if (n == 3)       { ph.nsB = ew[3][1]; ph.nskip = mkslot(1); }
        else if (n >= 10) { ph.nsB = ew[n][1]; ph.nskip = mkslot(n - 10); }
      }
    } else {  // enc63 -> An[dec0], Pn[0]
      ph.anext = 0; ph.nsA = 2.f * dw[0][0];
      ph.pnext = 0; ph.qsA = 2.f;
    }
    if (ph.anext >= 0) {
      anull = (ph.nsA == 0.f && ph.nsB == 0.f);
      if (anull) ph.anext = -1;
    }
    phs[i] = ph;
  }
  // ---- decoder phases ----
  for (int i = 0; i < 64; ++i) {
    int p = 64 + i + (i >= 5 ? 1 : 0);
    int s = 64 + i;
    Phase ph; blank_phase(ph);
    ph.ebase = 1;
    ph.xd = i ? (i - 1) & 3 : -1;
    ph.hout = mkslot(s);
    if (!anull) ph.afrag = i & 3;
    ph.hpA = mkslot(i ? s - 1 : 63);
    ph.spA = i ? dw[i][0] : 2.f * dw[0][0];
    if (i == 3)       { ph.hpB = mkslot(64 + 1);  ph.spB = dw[i][1]; }
    else if (i == 4)  { ph.hpB = mkslot(64 + 3);  ph.spB = dw[i][1]; }
    else if (i >= 10) { ph.hpB = mkslot(s - 10);  ph.spB = dw[i][1]; }
    if (i < 63) {
      int n = i + 1;
      ph.anext = n & 3;
      if (n == 4) ph.nsA = dw[4][0] + dw[4][1];
      else {
        ph.nsA = dw[n][0];
        if (n == 3)       { ph.nsB = dw[3][1]; ph.nskip = mkslot(64 + 1); }
        else if (n >= 10) { ph.nsB = dw[n][1]; ph.nskip = mkslot(64 + n - 10); }
      }
    }
    // Pn producers
    if (i == 2)      { ph.pnext = 3; ph.qsA = 2.f; }                 // proj3 = 2*h2
    else if (i == 3) { /* Pn[4] deferred to dec4 */ }
    else if (i == 4) { ph.pnext = 1; ph.qsA = 1.f;                   // proj5 = h4
                       ph.p2next = 0; ph.q2sA = 1.f; ph.q2sB = 1.f;  // proj4 = h3+h4
                       ph.q2skip = mkslot(64 + 3); }
    else if (i < 63) {
      int n = i + 1;
      ph.pnext = n & 3; ph.qsA = 1.f;
      if (n == 2)       { ph.qsB = 1.f; ph.qskip = mkslot(64 + 0); }
      else if (n >= 10) { ph.qsB = 1.f; ph.qskip = mkslot(64 + n - 10); }
    }
    if (ph.anext >= 0) {
      bool z = (ph.nsA == 0.f && ph.nsB == 0.f);
      if (z) ph.anext = -1;
      anull = z;
    }
    // proj consumer (out[i]); i==4 deferred to phase 69
    if (i != 4) { ph.pfrag = i & 3; ph.pouti = i; ph.pxout = i & 3; }
    phs[p] = ph;
    if (i == 4) {
      Phase pp; blank_phase(pp);
      pp.ebase = 1;
      pp.pfrag = 0; pp.pouti = 4; pp.pxout = 0;   // proj4 standalone phase
      phs[69] = pp;
    }
  }
}

// ---------------- persistent kernel: 512 blocks x 8 waves, 16-row tiles ----------------
// waves = pure K-split (kq = wave): kq<4 -> 5 units from kq*5; kq>=4 -> 4 units
// from 20+(kq-4)*4. Each wave computes BOTH nf columns (no B duplication).
// g2 (i_n, units 0..3) lives entirely in wave 0. Epilogue: wave0->nf0, wave1->nf1.
__global__ __launch_bounds__(512, 4) void rae_persist(
    const Phase* __restrict__ phs,
    const unsigned short* __restrict__ Xe,
    const unsigned short* __restrict__ BgE,
    const unsigned short* __restrict__ BgD,
    const unsigned short* __restrict__ Blin,
    const float* __restrict__ bias,
    const float* __restrict__ linb,
    float* __restrict__ hring,
    unsigned short* __restrict__ AnB,
    unsigned short* __restrict__ PnB,
    unsigned short* __restrict__ XdB,
    float* __restrict__ out,
    unsigned* __restrict__ arr)
{
  const int tid = threadIdx.x;
  const int lane = tid & 63;
  const int wave = tid >> 6;                 // kq 0..7
  const int l15 = lane & 15, lq = lane >> 4;
  const int bid = blockIdx.x;
  const int mt = bid >> 5, ns = bid & 31;    // bid%8 == ns%8 -> XCD-pinned B slice
  const int nf0 = ns * 2;
  const int R0 = mt * 16;
  const int arow = R0 + l15;
  const int nu = (wave < 4) ? 5 : 4;
  const int u0 = (wave < 4) ? wave * 5 : 20 + (wave - 4) * 4;

  __shared__ f32x4 red[8][7][64];   // 56 KiB: [wave][g0n0,g0n1,g1n0,g1n1,g3n0,g3n1,g2n1]
  __shared__ Phase lph[NPH];        // ~12 KiB

  for (int idx = tid; idx < NPH * (int)(sizeof(Phase) / 4); idx += 512)
    ((int*)lph)[idx] = ((const int*)phs)[idx];
  __syncthreads();

#pragma unroll 1
  for (int p = 0; p < NPH; ++p) {
    const Phase& ph = lph[p];

    // ================= cell =================
    if (ph.hout >= 0) {
      const unsigned short* Bg = ph.ebase ? BgD : BgE;
      const float* bias4 = bias + (ph.ebase ? 4096 : 0);
      const bool xsys = (ph.xd >= 0);
      const unsigned short* xfrag = nullptr;
      if (ph.xe >= 0)      xfrag = Xe  + (size_t)ph.xe * 32768u;
      else if (ph.xd >= 0) xfrag = XdB + (size_t)ph.xd * 32768u;
      const unsigned short* afrag =
          (ph.afrag >= 0) ? AnB + (size_t)ph.afrag * 262144u : nullptr;

      // ---- stage A-fragment loads ----
      unsigned long long a0[5], a1[5];
#pragma unroll
      for (int j = 0; j < 5; ++j) {
        a0[j] = 0ull; a1[j] = 0ull;
        if (j < nu) {
          const int u = u0 + j;
          if (u < 4) {          // x units (wave 0 only)
            if (xfrag) {
              const unsigned short* b = xfrag + (((size_t)(u * 4 + lq)) * 256 + arow) * 8;
              if (xsys) { a0[j] = ld64_sys(b); a1[j] = ld64_sys(b + 4); }
              else      { a0[j] = *(const unsigned long long*)b;
                          a1[j] = *(const unsigned long long*)(b + 4); }
            }
          } else {              // h units (cross-block An -> sys)
            if (afrag) {
              const unsigned short* b = afrag + (((size_t)((u - 4) * 4 + lq)) * 256 + arow) * 8;
              a0[j] = ld64_sys(b); a1[j] = ld64_sys(b + 4);
            }
          }
        }
      }

      // ---- epilogue prefetches (waves 0,1; block-private cached hring) ----
      float hpv[4] = {0,0,0,0}, nskv[4] = {0,0,0,0},
            qskv[4] = {0,0,0,0}, q2skv[4] = {0,0,0,0};
      if (wave < 2) {
        const int colE = ns * 32 + wave * 16 + l15;
        const float* hpA = hring + (size_t)ph.hpA * 262144u;
        const float* hpB = hring + (size_t)ph.hpB * 262144u;
        const float* nsk = hring + (size_t)ph.nskip * 262144u;
        const float* qsk = hring + (size_t)ph.qskip * 262144u;
        const float* q2k = hring + (size_t)ph.q2skip * 262144u;
#pragma unroll
        for (int q = 0; q < 4; ++q) {
          const size_t o = (size_t)(R0 + lq * 4 + q) * HDIM + colE;
          float hv = 0.f;
          if (ph.spA != 0.f) hv = ph.spA * hpA[o];
          if (ph.spB != 0.f) hv = fmaf(ph.spB, hpB[o], hv);
          hpv[q] = hv;
          if (ph.anext >= 0 && ph.nsB != 0.f) nskv[q] = nsk[o];
          if (ph.pnext >= 0 && ph.qsB != 0.f) qskv[q] = qsk[o];
          if (ph.p2next >= 0) q2skv[q] = q2k[o];
        }
      }

      // ---- MFMA: per unit {g0,g1,(g2|g3)} x 2 nf ----
      const f32x4 zero = {0.f, 0.f, 0.f, 0.f};
      f32x4 acc[8];  // g0n0,g0n1,g1n0,g1n1,g2n0,g2n1,g3n0,g3n1
#pragma unroll
      for (int k = 0; k < 8; ++k) acc[k] = zero;
#pragma unroll
      for (int j = 0; j < 5; ++j) {
        if (j < nu) {
          const int u = u0 + j;
          short8 av = mk8(a0[j], a1[j]);
          const unsigned short* bb = Bg + ((size_t)(u * 64 + nf0) * 64 + lane) * 8;
          short8 b00 = *(const short8*)(bb);
          short8 b01 = *(const short8*)(bb + 512);
          short8 b10 = *(const short8*)(bb + GSTRIDE);
          short8 b11 = *(const short8*)(bb + GSTRIDE + 512);
          acc[0] = MFMA(av, b00, acc[0]); acc[1] = MFMA(av, b01, acc[1]);
          acc[2] = MFMA(av, b10, acc[2]); acc[3] = MFMA(av, b11, acc[3]);
          if (u < 4) {
            short8 b20 = *(const short8*)(bb + 2 * GSTRIDE);
            short8 b21 = *(const short8*)(bb + 2 * GSTRIDE + 512);
            acc[4] = MFMA(av, b20, acc[4]); acc[5] = MFMA(av, b21, acc[5]);
          } else {
            short8 b30 = *(const short8*)(bb + 3 * GSTRIDE);
            short8 b31 = *(const short8*)(bb + 3 * GSTRIDE + 512);
            acc[6] = MFMA(av, b30, acc[6]); acc[7] = MFMA(av, b31, acc[7]);
          }
        }
      }
      red[wave][0][lane] = acc[0]; red[wave][1][lane] = acc[1];
      red[wave][2][lane] = acc[2]; red[wave][3][lane] = acc[3];
      red[wave][4][lane] = acc[6]; red[wave][5][lane] = acc[7];
      if (wave == 0) red[0][6][lane] = acc[5];   // g2n1 handoff
      __syncthreads();

      if (wave < 2) {
        f32x4 s0, s1, s2, s3;
        if (wave == 0) {
          s0 = red[0][0][lane]; s1 = red[0][2][lane]; s3 = red[0][4][lane];
#pragma unroll
          for (int w = 1; w < 8; ++w) {
            s0 += red[w][0][lane]; s1 += red[w][2][lane]; s3 += red[w][4][lane];
          }
          s2 = acc[4];
        } else {
          s0 = red[0][1][lane]; s1 = red[0][3][lane]; s3 = red[0][5][lane];
#pragma unroll
          for (int w = 1; w < 8; ++w) {
            s0 += red[w][1][lane]; s1 += red[w][3][lane]; s3 += red[w][5][lane];
          }
          s2 = red[0][6][lane];
        }
        const int colE = ns * 32 + wave * 16 + l15;
        const float br = bias4[colE],            bz = bias4[HDIM + colE];
        const float bi = bias4[2 * HDIM + colE], bh = bias4[3 * HDIM + colE];
        const int fa = (colE >> 3) * 2048 + (colE & 7);
        float* hout = hring + (size_t)ph.hout * 262144u;
        unsigned short* anx = ph.anext  >= 0 ? AnB + (size_t)ph.anext  * 262144u : nullptr;
        unsigned short* pnx = ph.pnext  >= 0 ? PnB + (size_t)ph.pnext  * 262144u : nullptr;
        unsigned short* p2x = ph.p2next >= 0 ? PnB + (size_t)ph.p2next * 262144u : nullptr;
#pragma unroll
        for (int q = 0; q < 4; ++q) {
          const int row = R0 + lq * 4 + q;
          const float r  = sigm_(s0[q] + br);
          const float z  = sigm_(s1[q] + bz);
          const float nv = tanh_(s2[q] + bi + r * (s3[q] + bh));
          const float h  = (1.f - z) * nv + z * hpv[q];
          hout[(size_t)row * HDIM + colE] = h;
          if (anx) st_pair_bf(anx + fa + row * 8, lane, f2bf(ph.nsA * h + ph.nsB * nskv[q]));
          if (pnx) st_pair_bf(pnx + fa + row * 8, lane, f2bf(ph.qsA * h + ph.qsB * qskv[q]));
          if (p2x) st_pair_bf(p2x + fa + row * 8, lane, f2bf(ph.q2sA * h + ph.q2sB * q2skv[q]));
        }
      }
    }

    // ================= proj (blocks ns<8, col-tile ns) =================
    if (ph.pfrag >= 0 && ns < 8) {
      __syncthreads();   // protect red overlay from cell-sum readers
      const unsigned short* pf = PnB + (size_t)ph.pfrag * 262144u;
      const int rb = mt * 16;
      unsigned long long pa[8];
#pragma unroll
      for (int k0 = 0; k0 < 4; ++k0) {
        const int ks = wave * 4 + k0;
        const unsigned short* b0 = pf + (((size_t)(ks * 4 + lq)) * 256 + rb + l15) * 8;
        pa[2 * k0] = ld64_sys(b0); pa[2 * k0 + 1] = ld64_sys(b0 + 4);
      }
      const f32x4 zero = {0.f, 0.f, 0.f, 0.f};
      f32x4 pacc = zero;
#pragma unroll
      for (int k0 = 0; k0 < 4; ++k0) {
        const int ks = wave * 4 + k0;
        short8 av = mk8(pa[2 * k0], pa[2 * k0 + 1]);
        short8 b  = *(const short8*)(Blin + (((size_t)ks * 8 + ns) * 64 + lane) * 8);
        pacc = MFMA(av, b, pacc);
      }
      f32x4* r2 = &red[0][0][0];
      r2[wave * 64 + lane] = pacc;
      __syncthreads();
      if (wave == 0) {
        f32x4 s = r2[lane];
#pragma unroll
        for (int w = 1; w < 8; ++w) s += r2[w * 64 + lane];
        const int col = ns * 16 + l15;
        const float lb = linb[col];
        const int fx = (col >> 3) * 2048 + (col & 7);
        float* po = out + (size_t)ph.pouti * XDIM;
        unsigned short* px = XdB + (size_t)ph.pxout * 32768u;
#pragma unroll
        for (int q = 0; q < 4; ++q) {
          const int row = rb + lq * 4 + q;
          const float v = s[q] + lb;
          po[(size_t)row * ORS + col] = v;
          st_pair_bf(px + fx + row * 8, lane, f2bf(v));
        }
      }
    }

    // ================= fence-free group barrier =================
    asm volatile("s_waitcnt vmcnt(0)" ::: "memory");
    __syncthreads();
    if (tid == 0) st32_sys(&arr[(mt << 5) + ns], (unsigned)(p + 1));
    if (wave == 0) {
      const unsigned tgt = (unsigned)(p + 1);
      int guard = 0;
      for (;;) {
        unsigned v = ld32_sys(&arr[(mt << 5) + (lane & 31)]);
        if (__all(v >= tgt)) break;
        if (++guard > (1 << 22)) break;   // safety: fail-validate instead of hang
      }
    }
    __syncthreads();
  }
}

// ---------------- host ----------------
extern "C" void kernel_launch(void* const* d_in, const int* in_sizes, int n_in,
                              void* d_out, int out_size, void* d_ws, size_t ws_size,
                              hipStream_t stream)
{
  const float* input = (const float*)d_in[0];
  const float* eWih = (const float*)d_in[1];
  const float* eWhh = (const float*)d_in[2];
  const float* eBih = (const float*)d_in[3];
  const float* eBhh = (const float*)d_in[4];
  const float* dWih = (const float*)d_in[5];
  const float* dWhh = (const float*)d_in[6];
  const float* dBih = (const float*)d_in[7];
  const float* dBhh = (const float*)d_in[8];
  const float* linW = (const float*)d_in[9];
  const float* linb = (const float*)d_in[10];
  float* out = (float*)d_out;

  // workspace layout (bytes)
  //  BgE   @ 0          9,437,184
  //  BgD   @ 9,437,184  9,437,184
  //  Blin  @18,874,368    262,144
  //  bias  @19,136,512     32,768
  //  hring @19,169,280 12,582,912  (12 x 256x1024 f32)
  //  Xe    @31,752,192  4,194,304
  //  AnB   @35,946,496  2,097,152  (4 slots)
  //  PnB   @38,043,648  2,097,152  (4 slots)
  //  XdB   @40,140,800    262,144  (4 slots)
  //  phs   @40,402,944     16,384
  //  arr   @40,419,328      4,096
  if (ws_size < 40423424u) return;
  char* ws = (char*)d_ws;
  short* BgE  = (short*)ws;
  short* BgD  = BgE + EPACK;
  short* Blin = (short*)(ws + 18874368u);
  float* bias = (float*)(ws + 19136512u);
  float* hring = (float*)(ws + 19169280u);
  unsigned short* Xe  = (unsigned short*)(ws + 31752192u);
  unsigned short* AnB = (unsigned short*)(ws + 35946496u);
  unsigned short* PnB = (unsigned short*)(ws + 38043648u);
  unsigned short* XdB = (unsigned short*)(ws + 40140800u);
  Phase* phs = (Phase*)(ws + 40402944u);
  unsigned* arr = (unsigned*)(ws + 40419328u);

  pack_gates<<<4608, 256, 0, stream>>>(eWih, eWhh, dWih, dWhh, BgE);
  pack_lin<<<64, 256, 0, stream>>>(linW, Blin);
  pack_bias<<<32, 256, 0, stream>>>(eBih, eBhh, dBih, dBhh, bias);
  pack_x<<<1024, 256, 0, stream>>>(input, Xe);
  setup_phases<<<1, 64, 0, stream>>>(phs, arr);

  rae_persist<<<512, 512, 0, stream>>>(
      phs, Xe, (const unsigned short*)BgE, (const unsigned short*)BgD,
      (const unsigned short*)Blin, bias, linb,
      hring, AnB, PnB, XdB, out, arr);
}

// Round 6
// 1356.752 us; speedup vs baseline: 1.9437x; 1.9437x over previous
//
#include <hip/hip_runtime.h>
#include <cstdint>
#include <cstddef>

#define XDIM 128
#define HDIM 1024
#define ORS 8192   /* out/input row stride = T*XD */
#define NPH 129

typedef __attribute__((ext_vector_type(8))) short short8;
typedef __attribute__((ext_vector_type(4))) float f32x4;

static const size_t GSTRIDE = (size_t)36 * 64 * 64 * 8;  // shorts per gate group
static const size_t EPACK   = 4 * GSTRIDE;               // shorts per enc/dec pack

struct Phase {
  float spA, spB, nsA, nsB, qsA, qsB, q2sA, q2sB;
  int ebase, xe, xd, afrag;
  int hpA, hpB, nskip, qskip, q2skip;
  int anext, pnext, p2next, hout;
  int pfrag, pouti, pxout;
};
static_assert(sizeof(Phase) == 96, "phase size");

__device__ __forceinline__ unsigned short f2bf(float f) {
  union { float f; unsigned u; } c; c.f = f;
  unsigned u = c.u + (0x7fffu + ((c.u >> 16) & 1u));  // RNE; finite inputs
  return (unsigned short)(u >> 16);
}
__device__ __forceinline__ float sigm_(float x) { return 1.f / (1.f + __expf(-x)); }
__device__ __forceinline__ float tanh_(float x) { return 2.f / (1.f + __expf(-2.f * x)) - 1.f; }

__device__ __forceinline__ short8 cvt8(float4 a, float4 b) {
  short8 o;
  o[0] = (short)f2bf(a.x); o[1] = (short)f2bf(a.y); o[2] = (short)f2bf(a.z); o[3] = (short)f2bf(a.w);
  o[4] = (short)f2bf(b.x); o[5] = (short)f2bf(b.y); o[6] = (short)f2bf(b.z); o[7] = (short)f2bf(b.w);
  return o;
}

// ---- coherence-point (IF$) accesses: bypass L1+L2, NO cache maintenance ----
__device__ __forceinline__ unsigned long long ld64_sys(const unsigned short* p) {
  return __hip_atomic_load((const unsigned long long*)p, __ATOMIC_RELAXED,
                           __HIP_MEMORY_SCOPE_SYSTEM);
}
__device__ __forceinline__ unsigned ld32_sys(const unsigned* p) {
  return __hip_atomic_load(p, __ATOMIC_RELAXED, __HIP_MEMORY_SCOPE_SYSTEM);
}
__device__ __forceinline__ void st32_sys(unsigned* p, unsigned v) {
  __hip_atomic_store(p, v, __ATOMIC_RELAXED, __HIP_MEMORY_SCOPE_SYSTEM);
}
union U128 { unsigned long long u[2]; short8 v; };
__device__ __forceinline__ short8 mk8(unsigned long long a, unsigned long long b) {
  U128 u; u.u[0] = a; u.u[1] = b; return u.v;
}
// lane-pair (even/odd cols) combine -> one 4B coherent store by even lane
__device__ __forceinline__ void st_pair_bf(unsigned short* addr, int lane, unsigned short v) {
  unsigned other = (unsigned)__shfl_xor((int)(unsigned)v, 1);
  if ((lane & 1) == 0)
    st32_sys((unsigned*)addr, ((unsigned)v & 0xffffu) | (other << 16));
}

#define MFMA(a,b,c) __builtin_amdgcn_mfma_f32_16x16x32_bf16((a),(b),(c),0,0,0)

// ---------------- prep kernels ----------------
__global__ __launch_bounds__(256) void pack_gates(
    const float* __restrict__ eWih, const float* __restrict__ eWhh,
    const float* __restrict__ dWih, const float* __restrict__ dWhh,
    short* __restrict__ Bg)
{
  unsigned t = blockIdx.x * 256u + threadIdx.x;   // 2*4*36*64*64 = 1,179,648
  unsigned l  = t & 63u; t >>= 6;
  unsigned nf = t & 63u; t >>= 6;
  unsigned ks = t % 36u; t /= 36u;
  unsigned g  = t & 3u;  t >>= 2;
  if (t >= 2u) return;
  if ((g == 2u && ks >= 4u) || (g == 3u && ks < 4u)) return;
  const float* Wih = t ? dWih : eWih;
  const float* Whh = t ? dWhh : eWhh;
  int k = (int)(ks * 32u + (l >> 4) * 8u);
  int n = (int)(nf * 16u + (l & 15u));
  const float* src;
  if (g == 3u)      src = Whh + (size_t)(2048 + n) * HDIM + (k - XDIM);
  else if (g == 2u) src = Wih + (size_t)(2048 + n) * XDIM + k;
  else if (ks < 4u) src = Wih + (size_t)(g * HDIM + n) * XDIM + k;
  else              src = Whh + (size_t)(g * HDIM + n) * HDIM + (k - XDIM);
  float4 a = *(const float4*)src;
  float4 b = *(const float4*)(src + 4);
  size_t off = ((((size_t)t * 4u + g) * 36u + ks) * 64u + nf) * 64u + l;
  *(short8*)(Bg + off * 8u) = cvt8(a, b);
}

__global__ __launch_bounds__(256) void pack_lin(const float* __restrict__ linW,
                                                short* __restrict__ Bl)
{
  unsigned t = blockIdx.x * 256u + threadIdx.x;   // 32*8*64 = 16384
  unsigned l  = t & 63u; t >>= 6;
  unsigned nf = t & 7u;  t >>= 3;
  unsigned ks = t;
  if (ks >= 32u) return;
  int k = (int)(ks * 32u + (l >> 4) * 8u);
  int n = (int)(nf * 16u + (l & 15u));
  const float* src = linW + (size_t)n * HDIM + k;
  float4 a = *(const float4*)src;
  float4 b = *(const float4*)(src + 4);
  *(short8*)(Bl + (((size_t)ks * 8u + nf) * 64u + l) * 8u) = cvt8(a, b);
}

__global__ __launch_bounds__(256) void pack_bias(
    const float* __restrict__ eIh, const float* __restrict__ eHh,
    const float* __restrict__ dIh, const float* __restrict__ dHh,
    float* __restrict__ bias)  // [2][4][1024]
{
  unsigned t = blockIdx.x * 256u + threadIdx.x;
  if (t >= 8192u) return;
  unsigned n = t & 1023u, g = (t >> 10) & 3u, e = t >> 12;
  const float* bih = e ? dIh : eIh;
  const float* bhh = e ? dHh : eHh;
  float v;
  if (g == 0u)      v = bih[n] + bhh[n];
  else if (g == 1u) v = bih[HDIM + n] + bhh[HDIM + n];
  else if (g == 2u) v = bih[2 * HDIM + n];
  else              v = bhh[2 * HDIM + n];
  bias[t] = v;
}

// enc input -> frag-major bf16: Xe[i][ks4][lq4][row256][8]
__global__ __launch_bounds__(256) void pack_x(const float* __restrict__ in,
                                              unsigned short* __restrict__ Xe)
{
  unsigned t = blockIdx.x * 256u + threadIdx.x;   // 64*4*4*256 = 262,144
  unsigned row = t & 255u; t >>= 8;
  unsigned lq  = t & 3u;   t >>= 2;
  unsigned ks  = t & 3u;   t >>= 2;
  unsigned i   = t;
  if (i >= 64u) return;
  const float* src = in + (size_t)row * ORS + i * 128u + ks * 32u + lq * 8u;
  float4 a = *(const float4*)src;
  float4 b = *(const float4*)(src + 4);
  *(short8*)(Xe + ((((size_t)i * 4u + ks) * 4u + lq) * 256u + row) * 8u) = cvt8(a, b);
}

// ---------------- phase-table builder (1 thread) ----------------
__device__ __forceinline__ int mkslot(int s) { return s % 12; }

__device__ void blank_phase(Phase& ph) {
  ph.spA = ph.spB = ph.nsA = ph.nsB = ph.qsA = ph.qsB = ph.q2sA = ph.q2sB = 0.f;
  ph.ebase = 0; ph.xe = -1; ph.xd = -1; ph.afrag = -1;
  ph.hpA = ph.hpB = ph.nskip = ph.qskip = ph.q2skip = 0;
  ph.anext = ph.pnext = ph.p2next = -1; ph.hout = -1;
  ph.pfrag = -1; ph.pouti = -1; ph.pxout = -1;
}

__global__ void setup_phases(Phase* __restrict__ phs, unsigned* __restrict__ arr) {
  const int t = threadIdx.x;
  for (int k = t; k < 1024; k += 64) arr[k] = 0u;   // zero barrier slots
  if (t != 0) return;

  // numpy-legacy MT19937, RandomState(0)
  unsigned mt[624];
  mt[0] = 0u;
  for (int i = 1; i < 624; ++i)
    mt[i] = 1812433253u * (mt[i - 1] ^ (mt[i - 1] >> 30)) + (unsigned)i;
  for (int i = 0; i < 624; ++i) {
    unsigned y = (mt[i] & 0x80000000u) | (mt[(i + 1) % 624] & 0x7fffffffu);
    unsigned v = mt[(i + 397) % 624] ^ (y >> 1);
    mt[i] = (y & 1u) ? (v ^ 0x9908b0dfu) : v;
  }
  int mti = 0;
  float ew[64][2], dw[64][2];
  for (int e = 0; e < 2; ++e) {
    for (int i = 0; i < 64; ++i) {
      unsigned y = mt[mti++];
      y ^= y >> 11; y ^= (y << 7) & 0x9d2c5680u; y ^= (y << 15) & 0xefc60000u; y ^= y >> 18;
      int w1 = (int)(y & 1u);
      int w2 = 1;
      if (w1 != 0) {
        unsigned z = mt[mti++];
        z ^= z >> 11; z ^= (z << 7) & 0x9d2c5680u; z ^= (z << 15) & 0xefc60000u; z ^= z >> 18;
        w2 = (int)(z & 1u);
      }
      if (e == 0) { ew[i][0] = (float)w1; ew[i][1] = (float)w2; }
      else        { dw[i][0] = (float)w1; dw[i][1] = (float)w2; }
    }
  }

  bool anull = true;  // An consumed by next cell phase is all-zero?
  // ---- encoder phases 0..63 (global step s = i) ----
  for (int i = 0; i < 64; ++i) {
    Phase ph; blank_phase(ph);
    ph.ebase = 0; ph.xe = i;
    ph.hout = mkslot(i);
    if (i >= 1 && !anull) ph.afrag = i & 3;
    ph.hpA = mkslot(i >= 1 ? i - 1 : 0);
    ph.spA = i ? ew[i][0] : 0.f;
    if (i == 3)       { ph.hpB = mkslot(1);      ph.spB = ew[i][1]; }
    else if (i == 4)  { ph.hpB = mkslot(3);      ph.spB = ew[i][1]; }
    else if (i >= 10) { ph.hpB = mkslot(i - 10); ph.spB = ew[i][1]; }
    if (i < 63) {
      int n = i + 1;
      ph.anext = n & 3;
      if (n == 4) ph.nsA = ew[4][0] + ew[4][1];      // skip source IS h_new (h3)
      else {
        ph.nsA = ew[n][0];
        if (n == 3)       { ph.nsB = ew[3][1]; ph.nskip = mkslot(1); }
        else if (n >= 10) { ph.nsB = ew[n][1]; ph.nskip = mkslot(n - 10); }
      }
    } else {  // enc63 -> An[dec0], Pn[0]
      ph.anext = 0; ph.nsA = 2.f * dw[0][0];
      ph.pnext = 0; ph.qsA = 2.f;
    }
    if (ph.anext >= 0) {
      anull = (ph.nsA == 0.f && ph.nsB == 0.f);
      if (anull) ph.anext = -1;
    }
    phs[i] = ph;
  }
  // ---- decoder phases ----
  for (int i = 0; i < 64; ++i) {
    int p = 64 + i + (i >= 5 ? 1 : 0);
    int s = 64 + i;
    Phase ph; blank_phase(ph);
    ph.ebase = 1;
    ph.xd = i ? (i - 1) & 3 : -1;
    ph.hout = mkslot(s);
    if (!anull) ph.afrag = i & 3;
    ph.hpA = mkslot(i ? s - 1 : 63);
    ph.spA = i ? dw[i][0] : 2.f * dw[0][0];
    if (i == 3)       { ph.hpB = mkslot(64 + 1);  ph.spB = dw[i][1]; }
    else if (i == 4)  { ph.hpB = mkslot(64 + 3);  ph.spB = dw[i][1]; }
    else if (i >= 10) { ph.hpB = mkslot(s - 10);  ph.spB = dw[i][1]; }
    if (i < 63) {
      int n = i + 1;
      ph.anext = n & 3;
      if (n == 4) ph.nsA = dw[4][0] + dw[4][1];
      else {
        ph.nsA = dw[n][0];
        if (n == 3)       { ph.nsB = dw[3][1]; ph.nskip = mkslot(64 + 1); }
        else if (n >= 10) { ph.nsB = dw[n][1]; ph.nskip = mkslot(64 + n - 10); }
      }
    }
    // Pn producers
    if (i == 2)      { ph.pnext = 3; ph.qsA = 2.f; }                 // proj3 = 2*h2
    else if (i == 3) { /* Pn[4] deferred to dec4 */ }
    else if (i == 4) { ph.pnext = 1; ph.qsA = 1.f;                   // proj5 = h4
                       ph.p2next = 0; ph.q2sA = 1.f; ph.q2sB = 1.f;  // proj4 = h3+h4
                       ph.q2skip = mkslot(64 + 3); }
    else if (i < 63) {
      int n = i + 1;
      ph.pnext = n & 3; ph.qsA = 1.f;
      if (n == 2)       { ph.qsB = 1.f; ph.qskip = mkslot(64 + 0); }
      else if (n >= 10) { ph.qsB = 1.f; ph.qskip = mkslot(64 + n - 10); }
    }
    if (ph.anext >= 0) {
      bool z = (ph.nsA == 0.f && ph.nsB == 0.f);
      if (z) ph.anext = -1;
      anull = z;
    }
    // proj consumer (out[i]); i==4 deferred to phase 69
    if (i != 4) { ph.pfrag = i & 3; ph.pouti = i; ph.pxout = i & 3; }
    phs[p] = ph;
    if (i == 4) {
      Phase pp; blank_phase(pp);
      pp.ebase = 1;
      pp.pfrag = 0; pp.pouti = 4; pp.pxout = 0;   // proj4 standalone phase
      phs[69] = pp;
    }
  }
}

// ---------------- persistent kernel: 256 blocks x 8 waves, 32-row x 32-col tiles ----
// wave w: x-unit w (w<4), h-units {hu0 + 8k, k=0..3} where hu0 = w<4 ? w+8 : w.
// Each wave computes BOTH nf columns (no B duplication). x g0/g1 fold into h acc.
// Epilogue: waves 0-3 by (rf,nf). Enc x-part + h_prev prefetch overlap the barrier.
__global__ __launch_bounds__(512, 2) void rae_persist(
    const Phase* __restrict__ phs,
    const unsigned short* __restrict__ Xe,
    const unsigned short* __restrict__ BgE,
    const unsigned short* __restrict__ BgD,
    const unsigned short* __restrict__ Blin,
    const float* __restrict__ bias,
    const float* __restrict__ linb,
    float* __restrict__ hring,
    unsigned short* __restrict__ AnB,
    unsigned short* __restrict__ PnB,
    unsigned short* __restrict__ XdB,
    float* __restrict__ out,
    unsigned* __restrict__ arr)
{
  const int tid = threadIdx.x;
  const int lane = tid & 63;
  const int wave = tid >> 6;
  const int l15 = lane & 15, lq = lane >> 4;
  const int bid = blockIdx.x;
  const int mt = bid >> 5, ns = bid & 31;    // bid%8 == ns%8 -> XCD-pinned B slice
  const int nf0 = ns * 2;
  const int R0 = mt * 32;
  const int hu0 = (wave < 4) ? wave + 8 : wave;

  __shared__ f32x4 red[8][2][6][64];    // 96 KiB: [wave][rf][g0n0,g0n1,g1n0,g1n1,g3n0,g3n1]
  __shared__ f32x4 red2[4][2][2][64];   // 16 KiB: [wave<4][rf][nf] g2 partials
  __shared__ f32x4 red3[8][2][64];      // 16 KiB: proj partials [wave][rf]
  __shared__ Phase lph[NPH];            // ~12 KiB

  for (int idx = tid; idx < NPH * (int)(sizeof(Phase) / 4); idx += 512)
    ((int*)lph)[idx] = ((const int*)phs)[idx];
  __syncthreads();

#pragma unroll 1
  for (int p = 0; p < NPH; ++p) {
    const Phase& ph = lph[p];
    const bool cell = (ph.hout >= 0);
    const bool proj = (ph.pfrag >= 0) && (ns < 8);
    const unsigned short* Bg = ph.ebase ? BgD : BgE;
    const float* bias4 = bias + (ph.ebase ? 4096 : 0);

    const f32x4 zero = {0.f, 0.f, 0.f, 0.f};
    f32x4 acc[2][6];   // [rf][g0n0,g0n1,g1n0,g1n1,g3n0,g3n1]
    f32x4 g2a[2][2];   // [rf][n0,n1]
#pragma unroll
    for (int rf = 0; rf < 2; ++rf) {
#pragma unroll
      for (int s = 0; s < 6; ++s) acc[rf][s] = zero;
      g2a[rf][0] = zero; g2a[rf][1] = zero;
    }

    auto do_x = [&](const unsigned short* xf, bool sys) {
      const unsigned short* bb = Bg + ((size_t)(wave * 64 + nf0) * 64 + lane) * 8;
      short8 b00 = *(const short8*)(bb);
      short8 b01 = *(const short8*)(bb + 512);
      short8 b10 = *(const short8*)(bb + GSTRIDE);
      short8 b11 = *(const short8*)(bb + GSTRIDE + 512);
      short8 b20 = *(const short8*)(bb + 2 * GSTRIDE);
      short8 b21 = *(const short8*)(bb + 2 * GSTRIDE + 512);
#pragma unroll
      for (int rf = 0; rf < 2; ++rf) {
        const unsigned short* a = xf + (((size_t)(wave * 4 + lq)) * 256 + R0 + rf * 16 + l15) * 8;
        short8 av;
        if (sys) av = mk8(ld64_sys(a), ld64_sys(a + 4));
        else     av = *(const short8*)a;
        acc[rf][0] = MFMA(av, b00, acc[rf][0]);
        acc[rf][1] = MFMA(av, b01, acc[rf][1]);
        acc[rf][2] = MFMA(av, b10, acc[rf][2]);
        acc[rf][3] = MFMA(av, b11, acc[rf][3]);
        g2a[rf][0] = MFMA(av, b20, g2a[rf][0]);
        g2a[rf][1] = MFMA(av, b21, g2a[rf][1]);
      }
    };

    // ---- pre-poll overlap: epilogue prefetch (block-local) + enc x-part ----
    float hpv[4] = {0,0,0,0}, nskv[4] = {0,0,0,0},
          qskv[4] = {0,0,0,0}, q2skv[4] = {0,0,0,0};
    if (cell && wave < 4) {
      const int erf = wave >> 1, enf = wave & 1;
      const int colE = ns * 32 + enf * 16 + l15;
      const float* hpA = hring + (size_t)ph.hpA * 262144u;
      const float* hpB = hring + (size_t)ph.hpB * 262144u;
      const float* nsk = hring + (size_t)ph.nskip * 262144u;
      const float* qsk = hring + (size_t)ph.qskip * 262144u;
      const float* q2k = hring + (size_t)ph.q2skip * 262144u;
#pragma unroll
      for (int q = 0; q < 4; ++q) {
        const size_t o = (size_t)(R0 + erf * 16 + lq * 4 + q) * HDIM + colE;
        float hv = 0.f;
        if (ph.spA != 0.f) hv = ph.spA * hpA[o];
        if (ph.spB != 0.f) hv = fmaf(ph.spB, hpB[o], hv);
        hpv[q] = hv;
        if (ph.anext >= 0 && ph.nsB != 0.f) nskv[q] = nsk[o];
        if (ph.pnext >= 0 && ph.qsB != 0.f) qskv[q] = qsk[o];
        if (ph.p2next >= 0) q2skv[q] = q2k[o];
      }
    }
    if (cell && wave < 4 && ph.xe >= 0)
      do_x(Xe + (size_t)ph.xe * 32768u, false);

    // ---- poll (all waves independently) ----
    if (p > 0) {
      int guard = 0;
      for (;;) {
        unsigned v = ld32_sys(&arr[(mt << 5) + (lane & 31)]);
        if (__all(v >= (unsigned)p)) break;
        if (++guard > (1 << 22)) break;   // safety: fail-validate instead of hang
      }
    }

    // ---- post-poll: dec x-part (Xd is cross-block) ----
    if (cell && wave < 4 && ph.xd >= 0)
      do_x(XdB + (size_t)ph.xd * 32768u, true);

    // ---- h part: stage all An loads, then MFMA ----
    if (cell && ph.afrag >= 0) {
      const unsigned short* af = AnB + (size_t)ph.afrag * 262144u;
      unsigned long long ha0[4][2], ha1[4][2];
#pragma unroll
      for (int k = 0; k < 4; ++k) {
        const int u = hu0 + 8 * k;
#pragma unroll
        for (int rf = 0; rf < 2; ++rf) {
          const unsigned short* b =
              af + (((size_t)((u - 4) * 4 + lq)) * 256 + R0 + rf * 16 + l15) * 8;
          ha0[k][rf] = ld64_sys(b); ha1[k][rf] = ld64_sys(b + 4);
        }
      }
#pragma unroll
      for (int k = 0; k < 4; ++k) {
        const int u = hu0 + 8 * k;
        const unsigned short* bb = Bg + ((size_t)(u * 64 + nf0) * 64 + lane) * 8;
        short8 b00 = *(const short8*)(bb);
        short8 b01 = *(const short8*)(bb + 512);
        short8 b10 = *(const short8*)(bb + GSTRIDE);
        short8 b11 = *(const short8*)(bb + GSTRIDE + 512);
        short8 b30 = *(const short8*)(bb + 3 * GSTRIDE);
        short8 b31 = *(const short8*)(bb + 3 * GSTRIDE + 512);
#pragma unroll
        for (int rf = 0; rf < 2; ++rf) {
          short8 av = mk8(ha0[k][rf], ha1[k][rf]);
          acc[rf][0] = MFMA(av, b00, acc[rf][0]);
          acc[rf][1] = MFMA(av, b01, acc[rf][1]);
          acc[rf][2] = MFMA(av, b10, acc[rf][2]);
          acc[rf][3] = MFMA(av, b11, acc[rf][3]);
          acc[rf][4] = MFMA(av, b30, acc[rf][4]);
          acc[rf][5] = MFMA(av, b31, acc[rf][5]);
        }
      }
    }

    // ---- write partials ----
    if (cell) {
#pragma unroll
      for (int rf = 0; rf < 2; ++rf) {
#pragma unroll
        for (int s = 0; s < 6; ++s) red[wave][rf][s][lane] = acc[rf][s];
      }
      if (wave < 4) {
#pragma unroll
        for (int rf = 0; rf < 2; ++rf) {
          red2[wave][rf][0][lane] = g2a[rf][0];
          red2[wave][rf][1][lane] = g2a[rf][1];
        }
      }
    }
    __syncthreads();   // sync1

    // ---- epilogue (waves 0-3: combo (rf,nf)) ----
    if (cell && wave < 4) {
      const int erf = wave >> 1, enf = wave & 1;
      f32x4 S0 = zero, S1 = zero, S3 = zero, S2 = zero;
#pragma unroll
      for (int w = 0; w < 8; ++w) {
        S0 += red[w][erf][0 + enf][lane];
        S1 += red[w][erf][2 + enf][lane];
        S3 += red[w][erf][4 + enf][lane];
      }
#pragma unroll
      for (int w = 0; w < 4; ++w) S2 += red2[w][erf][enf][lane];
      const int colE = ns * 32 + enf * 16 + l15;
      const float br = bias4[colE],            bz = bias4[HDIM + colE];
      const float bi = bias4[2 * HDIM + colE], bh = bias4[3 * HDIM + colE];
      const int fa = (colE >> 3) * 2048 + (colE & 7);
      float* hout = hring + (size_t)ph.hout * 262144u;
      unsigned short* anx = ph.anext  >= 0 ? AnB + (size_t)ph.anext  * 262144u : nullptr;
      unsigned short* pnx = ph.pnext  >= 0 ? PnB + (size_t)ph.pnext  * 262144u : nullptr;
      unsigned short* p2x = ph.p2next >= 0 ? PnB + (size_t)ph.p2next * 262144u : nullptr;
#pragma unroll
      for (int q = 0; q < 4; ++q) {
        const int row = R0 + erf * 16 + lq * 4 + q;
        const float r  = sigm_(S0[q] + br);
        const float z  = sigm_(S1[q] + bz);
        const float nv = tanh_(S2[q] + bi + r * (S3[q] + bh));
        const float h  = (1.f - z) * nv + z * hpv[q];
        if (anx) st_pair_bf(anx + fa + row * 8, lane, f2bf(ph.nsA * h + ph.nsB * nskv[q]));
        if (pnx) st_pair_bf(pnx + fa + row * 8, lane, f2bf(ph.qsA * h + ph.qsB * qskv[q]));
        if (p2x) st_pair_bf(p2x + fa + row * 8, lane, f2bf(ph.q2sA * h + ph.q2sB * q2skv[q]));
        hout[(size_t)row * HDIM + colE] = h;
      }
    }

    // ---- proj (blocks ns<8; 8-wave K-split over 32 rows) ----
    if (proj) {
      const unsigned short* pf = PnB + (size_t)ph.pfrag * 262144u;
      unsigned long long q0[4][2], q1[4][2];
#pragma unroll
      for (int k0 = 0; k0 < 4; ++k0) {
        const int ks = wave * 4 + k0;
#pragma unroll
        for (int rf = 0; rf < 2; ++rf) {
          const unsigned short* a =
              pf + (((size_t)(ks * 4 + lq)) * 256 + R0 + rf * 16 + l15) * 8;
          q0[k0][rf] = ld64_sys(a); q1[k0][rf] = ld64_sys(a + 4);
        }
      }
      f32x4 pacc0 = zero, pacc1 = zero;
#pragma unroll
      for (int k0 = 0; k0 < 4; ++k0) {
        const int ks = wave * 4 + k0;
        short8 b = *(const short8*)(Blin + (((size_t)ks * 8 + ns) * 64 + lane) * 8);
        pacc0 = MFMA(mk8(q0[k0][0], q1[k0][0]), b, pacc0);
        pacc1 = MFMA(mk8(q0[k0][1], q1[k0][1]), b, pacc1);
      }
      red3[wave][0][lane] = pacc0;
      red3[wave][1][lane] = pacc1;
    }
    if (ph.pfrag >= 0 && ns < 8) __syncthreads();   // sync2 (block-uniform)
    if (proj && wave == 0) {
      const int col = ns * 16 + l15;
      const float lb = linb[col];
      const int fx = (col >> 3) * 2048 + (col & 7);
      float* po = out + (size_t)ph.pouti * XDIM;
      unsigned short* px = XdB + (size_t)ph.pxout * 32768u;
#pragma unroll
      for (int rf = 0; rf < 2; ++rf) {
        f32x4 S = red3[0][rf][lane];
#pragma unroll
        for (int w = 1; w < 8; ++w) S += red3[w][rf][lane];
#pragma unroll
        for (int q = 0; q < 4; ++q) {
          const int row = R0 + rf * 16 + lq * 4 + q;
          const float v = S[q] + lb;
          po[(size_t)row * ORS + col] = v;
          st_pair_bf(px + fx + row * 8, lane, f2bf(v));
        }
      }
    }

    // ---- drain + flag ----
    asm volatile("s_waitcnt vmcnt(0)" ::: "memory");
    __syncthreads();   // sync3
    if (tid == 0) st32_sys(&arr[(mt << 5) + ns], (unsigned)(p + 1));
  }
}

// ---------------- host ----------------
extern "C" void kernel_launch(void* const* d_in, const int* in_sizes, int n_in,
                              void* d_out, int out_size, void* d_ws, size_t ws_size,
                              hipStream_t stream)
{
  const float* input = (const float*)d_in[0];
  const float* eWih = (const float*)d_in[1];
  const float* eWhh = (const float*)d_in[2];
  const float* eBih = (const float*)d_in[3];
  const float* eBhh = (const float*)d_in[4];
  const float* dWih = (const float*)d_in[5];
  const float* dWhh = (const float*)d_in[6];
  const float* dBih = (const float*)d_in[7];
  const float* dBhh = (const float*)d_in[8];
  const float* linW = (const float*)d_in[9];
  const float* linb = (const float*)d_in[10];
  float* out = (float*)d_out;

  // workspace layout (bytes)
  //  BgE   @ 0          9,437,184
  //  BgD   @ 9,437,184  9,437,184
  //  Blin  @18,874,368    262,144
  //  bias  @19,136,512     32,768
  //  hring @19,169,280 12,582,912  (12 x 256x1024 f32)
  //  Xe    @31,752,192  4,194,304
  //  AnB   @35,946,496  2,097,152  (4 slots)
  //  PnB   @38,043,648  2,097,152  (4 slots)
  //  XdB   @40,140,800    262,144  (4 slots)
  //  phs   @40,402,944     16,384
  //  arr   @40,419,328      4,096
  if (ws_size < 40423424u) return;
  char* ws = (char*)d_ws;
  short* BgE  = (short*)ws;
  short* BgD  = BgE + EPACK;
  short* Blin = (short*)(ws + 18874368u);
  float* bias = (float*)(ws + 19136512u);
  float* hring = (float*)(ws + 19169280u);
  unsigned short* Xe  = (unsigned short*)(ws + 31752192u);
  unsigned short* AnB = (unsigned short*)(ws + 35946496u);
  unsigned short* PnB = (unsigned short*)(ws + 38043648u);
  unsigned short* XdB = (unsigned short*)(ws + 40140800u);
  Phase* phs = (Phase*)(ws + 40402944u);
  unsigned* arr = (unsigned*)(ws + 40419328u);

  pack_gates<<<4608, 256, 0, stream>>>(eWih, eWhh, dWih, dWhh, BgE);
  pack_lin<<<64, 256, 0, stream>>>(linW, Blin);
  pack_bias<<<32, 256, 0, stream>>>(eBih, eBhh, dBih, dBhh, bias);
  pack_x<<<1024, 256, 0, stream>>>(input, Xe);
  setup_phases<<<1, 64, 0, stream>>>(phs, arr);

  rae_persist<<<256, 512, 0, stream>>>(
      phs, Xe, (const unsigned short*)BgE, (const unsigned short*)BgD,
      (const unsigned short*)Blin, bias, linb,
      hring, AnB, PnB, XdB, out, arr);
}